// Round 2
// baseline (745.843 us; speedup 1.0000x reference)
//
#include <hip/hip_runtime.h>
#include <cstdint>
#include <cstddef>

// Problem constants
#define BB 4
#define SS 4096
#define DD 1024
#define HH 16
#define MM (BB*SS)          // 16384 rows

typedef __bf16 bf16x8 __attribute__((ext_vector_type(8)));
typedef float  f32x4  __attribute__((ext_vector_type(4)));

__device__ __forceinline__ float b2f(unsigned short h){
    union { unsigned int u; float f; } c; c.u = ((unsigned int)h) << 16; return c.f;
}
__device__ __forceinline__ float b2f_u(unsigned int u16){
    union { unsigned int u; float f; } c; c.u = u16 << 16; return c.f;
}
__device__ __forceinline__ unsigned short f2b(float f){
    union { float f; unsigned int u; } c; c.f = f;
    unsigned int u = c.u + 0x7FFFu + ((c.u >> 16) & 1u);   // RNE
    return (unsigned short)(u >> 16);
}

// ---------------------------------------------------------------- transpose+cvt
__global__ void transpose_cvt(const float* __restrict__ src, unsigned short* __restrict__ dst,
                              int K, int N){
    __shared__ float tile[32][33];
    int kb = blockIdx.y*32, nb = blockIdx.x*32;
    int tx = threadIdx.x, ty = threadIdx.y;
    for(int i=0;i<32;i+=8) tile[ty+i][tx] = src[(size_t)(kb+ty+i)*N + nb+tx];
    __syncthreads();
    for(int i=0;i<32;i+=8) dst[(size_t)(nb+ty+i)*K + kb+tx] = f2b(tile[tx][ty+i]);
}

// ---------------------------------------------------------------- layernorm (+ optional sinusoidal PE)
template<int INBF>
__global__ __launch_bounds__(256) void ln_kernel(const void* __restrict__ xin,
                                                 const float* __restrict__ g,
                                                 const float* __restrict__ bta,
                                                 unsigned short* __restrict__ out,
                                                 int add_pe){
    int row = blockIdx.x;
    int t = threadIdx.x;
    float4 v;
    if (INBF == 0) {
        v = ((const float4*)((const float*)xin + (size_t)row*DD))[t];
    } else {
        ushort4 u = ((const ushort4*)((const unsigned short*)xin + (size_t)row*DD))[t];
        v.x = b2f(u.x); v.y = b2f(u.y); v.z = b2f(u.z); v.w = b2f(u.w);
    }
    float s = v.x+v.y+v.z+v.w;
    float q = v.x*v.x+v.y*v.y+v.z*v.z+v.w*v.w;
    for(int off=32; off>0; off>>=1){ s += __shfl_xor(s, off); q += __shfl_xor(q, off); }
    __shared__ float red[8];
    int wv = t>>6, ln = t&63;
    if(ln==0){ red[wv] = s; red[4+wv] = q; }
    __syncthreads();
    s = red[0]+red[1]+red[2]+red[3];
    q = red[4]+red[5]+red[6]+red[7];
    float mu = s * (1.0f/1024.0f);
    float var = q * (1.0f/1024.0f) - mu*mu;
    float rs = rsqrtf(var + 1e-6f);
    int d0 = t*4;
    float4 gg = ((const float4*)g)[t];
    float4 bb = ((const float4*)bta)[t];
    float o0 = (v.x-mu)*rs*gg.x + bb.x;
    float o1 = (v.y-mu)*rs*gg.y + bb.y;
    float o2 = (v.z-mu)*rs*gg.z + bb.z;
    float o3 = (v.w-mu)*rs*gg.w + bb.w;
    if(add_pe){
        int sidx = row & (SS-1);
        const float cfac = -0.008994473019508968f;   // -ln(10000)/1024
        float a0 = (float)sidx * expf(cfac * (float)(d0));
        float a1 = (float)sidx * expf(cfac * (float)(d0 + 2));
        o0 += sinf(a0); o1 += cosf(a0);
        o2 += sinf(a1); o3 += cosf(a1);
    }
    ushort4 o;
    o.x = f2b(o0); o.y = f2b(o1); o.z = f2b(o2); o.w = f2b(o3);
    *(ushort4*)(out + (size_t)row*DD + d0) = o;
}

// ---------------------------------------------------------------- 256x256 8-phase bf16 MFMA GEMM
// C = A[M,K] * Bt[N,K]^T.  8 waves (2M x 4N), BK=64, 2 K-tiles per iteration.
// LDS: 2 dbuf x 2 regions x 128x64 bf16 for A and B = 128 KiB.
// A region h holds rows {wr*128 + h*64 + 0..63 : wr=0,1} (quadrant-row split) so each
// region's reads complete one phase before its stage-overwrite is issued.
// B region q holds rows {wc*64 + q*32 + 0..31 : wc=0..3}.
// vmcnt(6) only at phases 4 and 8 (3 half-tiles = 6 loads stay in flight).
// EPI as before.

#define BARX __builtin_amdgcn_s_barrier()
#define LGK0 { asm volatile("s_waitcnt lgkmcnt(0)" ::: "memory"); __builtin_amdgcn_sched_barrier(0); }
#define LGK8 asm volatile("s_waitcnt lgkmcnt(8)" ::: "memory")
#define VM6  asm volatile("s_waitcnt vmcnt(6)" ::: "memory")
#define PRIO1 __builtin_amdgcn_s_setprio(1)
#define PRIO0 __builtin_amdgcn_s_setprio(0)

#define LDA(D, QR) { \
    const char* _pa = sA + (((D)*2+(QR))<<14) + rbaseA; \
    _Pragma("unroll") \
    for (int mi = 0; mi < 4; mi++) { \
        ra[mi][0] = *(const bf16x8*)(_pa + (mi<<11) + kb0); \
        ra[mi][1] = *(const bf16x8*)(_pa + (mi<<11) + kb1); \
    } }

#define LDB(RB, D, QC) { \
    const char* _pb = sB + (((D)*2+(QC))<<14) + rbaseB; \
    _Pragma("unroll") \
    for (int nj = 0; nj < 2; nj++) { \
        RB[nj][0] = *(const bf16x8*)(_pb + (nj<<11) + kb0); \
        RB[nj][1] = *(const bf16x8*)(_pb + (nj<<11) + kb1); \
    } }

#define MMAC(RB, QR, QC) { \
    _Pragma("unroll") \
    for (int mi = 0; mi < 4; mi++) \
    _Pragma("unroll") \
    for (int nj = 0; nj < 2; nj++) \
    _Pragma("unroll") \
    for (int kk = 0; kk < 2; kk++) \
        acc[(QR)*4+mi][(QC)*2+nj] = __builtin_amdgcn_mfma_f32_16x16x32_bf16( \
            ra[mi][kk], RB[nj][kk], acc[(QR)*4+mi][(QC)*2+nj], 0, 0, 0); }

#define STAGEA(D, H, KS) { \
    __builtin_amdgcn_global_load_lds((const __attribute__((address_space(1))) void*)(pA[H][0] + (KS)), \
        (__attribute__((address_space(3))) void*)(sA + (((D)*2+(H))<<14) + wbase), 16, 0, 0); \
    __builtin_amdgcn_global_load_lds((const __attribute__((address_space(1))) void*)(pA[H][1] + (KS)), \
        (__attribute__((address_space(3))) void*)(sA + (((D)*2+(H))<<14) + wbase + 8192), 16, 0, 0); }

#define STAGEB(D, Q, KS) { \
    __builtin_amdgcn_global_load_lds((const __attribute__((address_space(1))) void*)(pB[Q][0] + (KS)), \
        (__attribute__((address_space(3))) void*)(sB + (((D)*2+(Q))<<14) + wbase), 16, 0, 0); \
    __builtin_amdgcn_global_load_lds((const __attribute__((address_space(1))) void*)(pB[Q][1] + (KS)), \
        (__attribute__((address_space(3))) void*)(sB + (((D)*2+(Q))<<14) + wbase + 8192), 16, 0, 0); }

template<int EPI>
__global__ __launch_bounds__(512, 2) void gemm256(
        const unsigned short* __restrict__ A,
        const unsigned short* __restrict__ Bt,
        void* __restrict__ Cout,
        const float* __restrict__ bias,
        const void* __restrict__ resid,
        int M, int N, int K)
{
    __shared__ __align__(16) unsigned short lAbuf[2*2*128*64];   // 64 KiB
    __shared__ __align__(16) unsigned short lBbuf[2*2*128*64];   // 64 KiB
    char* sA = (char*)lAbuf;
    char* sB = (char*)lBbuf;

    const int tid  = threadIdx.x;
    const int lane = tid & 63;
    const int wave = tid >> 6;        // 0..7
    const int quad = lane >> 4;
    const int l16  = lane & 15;
    const int wr = wave >> 2;         // 0..1 (M)
    const int wc = wave & 3;          // 0..3 (N)

    // XCD-aware bijective tile swizzle (all grids here have nwg % 8 == 0)
    int gn  = gridDim.x;
    int lin = blockIdx.y * gn + blockIdx.x;
    int xcd = lin & 7;
    int j   = lin >> 3;
    int mt  = xcd + 8*(j/gn);
    int nt  = j - (j/gn)*gn;
    const int m0 = mt * 256;
    const int n0 = nt * 256;

    // per-thread stage source pointers (inverse-swizzled global, linear LDS dest)
    const unsigned short* pA[2][2];
    const unsigned short* pB[2][2];
    #pragma unroll
    for (int h = 0; h < 2; h++) {
        #pragma unroll
        for (int jj = 0; jj < 2; jj++) {
            int c  = tid + 512*jj;
            int lr = c >> 3;
            int kc = ((c & 7) ^ (lr & 7)) << 3;   // elements
            int ga = m0 + ((lr>>6)<<7) + h*64 + (lr & 63);
            int gb = n0 + ((lr>>5)<<6) + h*32 + (lr & 31);
            pA[h][jj] = A  + (size_t)ga * K + kc;
            pB[h][jj] = Bt + (size_t)gb * K + kc;
        }
    }
    const int wbase  = wave << 10;                    // lanes add lane*16
    const int rbaseA = (wr*64 + l16) * 128;
    const int rbaseB = (wc*32 + l16) * 128;
    const int kb0 = (quad*16)      ^ ((l16 & 7) << 4);
    const int kb1 = (64 + quad*16) ^ ((l16 & 7) << 4);

    f32x4 acc[8][4] = {};          // [qr*4+mi][qc*2+nj]
    bf16x8 ra[4][2], rb0[2][2], rb1[2][2];

    // ---- prologue: tile0 (d0: Aqr0,Bqc0,Bqc1,Aqr1) + tile1 (d1: Aqr0,Bqc0,Bqc1)
    STAGEA(0,0, 0); STAGEB(0,0, 0); STAGEB(0,1, 0); STAGEA(0,1, 0);
    STAGEA(1,0, 64); STAGEB(1,0, 64); STAGEB(1,1, 64);
    VM6;                            // tile0's 8 loads landed; 3 half-tiles in flight
    BARX;

    const int NIT = K >> 7;         // 2 K-tiles per iteration
    for (int it = 0; it < NIT; it++) {
        int ka  = it << 7;
        int kb_ = ka + 64;                       // tile 2i+1 (last half staged at p1)
        int kc2 = ka + 128; if (kc2 >= K) kc2 = 0;  // tile 2i+2 -> d0 (wrap: dummy, safe)
        int kc3 = ka + 192; if (kc3 >= K) kc3 = 0;  // tile 2i+3 -> d1

        // p1: read d0 A(qr0)+B(qc0); stage d1.Aqr1 (tile 2i+1 final half)
        LDA(0,0); LDB(rb0, 0,0);
        STAGEA(1,1, kb_);
        LGK8;
        BARX; LGK0; PRIO1; MMAC(rb0, 0,0); PRIO0; BARX;
        // p2: read d0 B(qc1); stage d0.Aqr0 (tile 2i+2)
        LDB(rb1, 0,1);
        STAGEA(0,0, kc2);
        BARX; LGK0; PRIO1; MMAC(rb1, 0,1); PRIO0; BARX;
        // p3: read d0 A(qr1); stage d0.Bqc0
        LDA(0,1);
        STAGEB(0,0, kc2);
        BARX; LGK0; PRIO1; MMAC(rb1, 1,1); PRIO0; BARX;
        // p4: no reads (rb0 held in regs); stage d0.Bqc1; counted vmcnt
        STAGEB(0,1, kc2);
        VM6;
        BARX; LGK0; PRIO1; MMAC(rb0, 1,0); PRIO0; BARX;
        // p5: read d1 A(qr0)+B(qc0); stage d0.Aqr1
        LDA(1,0); LDB(rb0, 1,0);
        STAGEA(0,1, kc2);
        LGK8;
        BARX; LGK0; PRIO1; MMAC(rb0, 0,0); PRIO0; BARX;
        // p6: read d1 B(qc1); stage d1.Aqr0 (tile 2i+3)
        LDB(rb1, 1,1);
        STAGEA(1,0, kc3);
        BARX; LGK0; PRIO1; MMAC(rb1, 0,1); PRIO0; BARX;
        // p7: read d1 A(qr1); stage d1.Bqc0
        LDA(1,1);
        STAGEB(1,0, kc3);
        BARX; LGK0; PRIO1; MMAC(rb1, 1,1); PRIO0; BARX;
        // p8: no reads; stage d1.Bqc1; counted vmcnt
        STAGEB(1,1, kc3);
        VM6;
        BARX; LGK0; PRIO1; MMAC(rb0, 1,0); PRIO0; BARX;
    }
    asm volatile("s_waitcnt vmcnt(0)" ::: "memory");   // drain before LDS dealloc

    // ---- epilogue
    #pragma unroll
    for (int qm = 0; qm < 8; qm++) {
        int grow0 = m0 + wr*128 + (qm>>2)*64 + (qm&3)*16 + quad*4;
        #pragma unroll
        for (int r = 0; r < 4; r++) {
            int grow = grow0 + r;
            #pragma unroll
            for (int ni = 0; ni < 4; ni++) {
                int gcol = n0 + wc*64 + ni*16 + l16;
                float v = acc[qm][ni][r];
                size_t idx = (size_t)grow * N + gcol;
                if (EPI == 0) {
                    ((unsigned short*)Cout)[idx] = f2b(v);
                } else if (EPI == 1) {
                    v += bias[gcol];
                    v = 0.5f * v * (1.0f + erff(v * 0.70710678118654752f));
                    ((unsigned short*)Cout)[idx] = f2b(v);
                } else if (EPI == 2) {
                    v += bias[gcol] + ((const float*)resid)[idx];
                    ((unsigned short*)Cout)[idx] = f2b(v);
                } else {
                    v += bias[gcol] + b2f(((const unsigned short*)resid)[idx]);
                    ((float*)Cout)[idx] = v;
                }
            }
        }
    }
}

// ---------------------------------------------------------------- context partials (k-softmax folded)
__global__ __launch_bounds__(256) void ctx_partial(const unsigned short* __restrict__ qkv,
                                                   float* __restrict__ EP,
                                                   float* __restrict__ CS){
    int sc = blockIdx.x, h = blockIdx.y, b = blockIdx.z;
    int t = threadIdx.x;
    __shared__ __align__(16) float kl[64][64];   // exp(k)
    __shared__ __align__(16) float vl[64][64];
    __shared__ float csred[4][64];
    float acc[4][4] = {};
    float cspart = 0.0f;
    int e4 = (t & 15) * 4, d4 = (t >> 4) * 4;
    int dcol = t & 63, schunk = t >> 6;
    for(int s0 = 0; s0 < 256; s0 += 64){
        __syncthreads();
        #pragma unroll
        for(int j=0;j<2;j++){
            int lin = t + 256*j;
            int row = lin >> 3;
            int c8  = (lin & 7) * 8;
            size_t gr = (size_t)(b*SS + sc*256 + s0 + row);
            uint4 kv = *(const uint4*)(qkv + gr*3072 + DD + h*64 + c8);
            float4 ka, kb2;
            ka.x = expf(b2f_u(kv.x & 0xFFFFu)); ka.y = expf(b2f_u(kv.x >> 16));
            ka.z = expf(b2f_u(kv.y & 0xFFFFu)); ka.w = expf(b2f_u(kv.y >> 16));
            kb2.x = expf(b2f_u(kv.z & 0xFFFFu)); kb2.y = expf(b2f_u(kv.z >> 16));
            kb2.z = expf(b2f_u(kv.w & 0xFFFFu)); kb2.w = expf(b2f_u(kv.w >> 16));
            *(float4*)&kl[row][c8]   = ka;
            *(float4*)&kl[row][c8+4] = kb2;
            uint4 vv = *(const uint4*)(qkv + gr*3072 + 2*DD + h*64 + c8);
            float4 va, vb;
            va.x = b2f_u(vv.x & 0xFFFFu); va.y = b2f_u(vv.x >> 16);
            va.z = b2f_u(vv.y & 0xFFFFu); va.w = b2f_u(vv.y >> 16);
            vb.x = b2f_u(vv.z & 0xFFFFu); vb.y = b2f_u(vv.z >> 16);
            vb.z = b2f_u(vv.w & 0xFFFFu); vb.w = b2f_u(vv.w >> 16);
            *(float4*)&vl[row][c8]   = va;
            *(float4*)&vl[row][c8+4] = vb;
        }
        __syncthreads();
        #pragma unroll
        for(int i=0;i<16;i++) cspart += kl[schunk*16+i][dcol];
        for(int s=0;s<64;s++){
            float4 k4 = *(const float4*)&kl[s][d4];
            float4 v4 = *(const float4*)&vl[s][e4];
            acc[0][0] += k4.x*v4.x; acc[0][1] += k4.x*v4.y; acc[0][2] += k4.x*v4.z; acc[0][3] += k4.x*v4.w;
            acc[1][0] += k4.y*v4.x; acc[1][1] += k4.y*v4.y; acc[1][2] += k4.y*v4.z; acc[1][3] += k4.y*v4.w;
            acc[2][0] += k4.z*v4.x; acc[2][1] += k4.z*v4.y; acc[2][2] += k4.z*v4.z; acc[2][3] += k4.z*v4.w;
            acc[3][0] += k4.w*v4.x; acc[3][1] += k4.w*v4.y; acc[3][2] += k4.w*v4.z; acc[3][3] += k4.w*v4.w;
        }
    }
    int slot = (b*HH + h)*16 + sc;
    float* ep = EP + (size_t)slot*4096;
    #pragma unroll
    for(int i=0;i<4;i++)
        *(float4*)&ep[(d4+i)*64 + e4] = *(float4*)&acc[i][0];
    csred[schunk][dcol] = cspart;
    __syncthreads();
    if(t < 64) CS[slot*64 + t] = csred[0][t]+csred[1][t]+csred[2][t]+csred[3][t];
}

// ---------------------------------------------------------------- reduce 16 slots, divide by colsum
__global__ __launch_bounds__(256) void ctx_reduce(const float* __restrict__ EP,
                                                  const float* __restrict__ CS,
                                                  float* __restrict__ CTXF){
    int bh = blockIdx.x;
    int t = threadIdx.x;
    int d = t >> 2, e0 = (t & 3) * 16;
    float cs = 0.0f;
    #pragma unroll
    for(int sl=0; sl<16; sl++) cs += CS[(bh*16+sl)*64 + d];
    float inv = 1.0f/cs;
    #pragma unroll
    for(int i=0;i<16;i++){
        float s = 0.0f;
        #pragma unroll
        for(int sl=0; sl<16; sl++) s += EP[(size_t)(bh*16+sl)*4096 + d*64 + e0 + i];
        CTXF[(size_t)bh*4096 + d*64 + e0 + i] = s * inv;
    }
}

// ---------------------------------------------------------------- attn = softmax(q)/8 @ ctx  (q-softmax fused)
__global__ __launch_bounds__(256) void attn_heads(const unsigned short* __restrict__ qkv,
                                                  const float* __restrict__ CTXF,
                                                  unsigned short* __restrict__ abuf){
    int rg = blockIdx.x, h = blockIdx.y;
    int b = rg >> 6;
    int t = threadIdx.x;
    __shared__ __align__(16) float cl[64][64];
    __shared__ __align__(16) float qlT[64*68];    // [d][r], row stride 68 floats
    const float* cb = CTXF + (size_t)(b*HH + h)*4096;
    for(int j=0;j<4;j++){
        int lin = t + 256*j;
        ((float4*)cl)[lin] = ((const float4*)cb)[lin];
    }
    {
        int r = t >> 2, seg = (t & 3) * 16;
        const unsigned short* qp = qkv + (size_t)(rg*64 + r)*3072 + h*64 + seg;
        float vals[16];
        float m = -1e30f;
        #pragma unroll
        for(int u=0; u<4; u++){
            ushort4 qv = *(const ushort4*)(qp + u*4);
            vals[u*4+0]=b2f(qv.x); vals[u*4+1]=b2f(qv.y); vals[u*4+2]=b2f(qv.z); vals[u*4+3]=b2f(qv.w);
        }
        #pragma unroll
        for(int i=0;i<16;i++) m = fmaxf(m, vals[i]);
        m = fmaxf(m, __shfl_xor(m, 1));
        m = fmaxf(m, __shfl_xor(m, 2));
        float ssum = 0.0f;
        #pragma unroll
        for(int i=0;i<16;i++){ vals[i] = expf(vals[i]-m); ssum += vals[i]; }
        ssum += __shfl_xor(ssum, 1);
        ssum += __shfl_xor(ssum, 2);
        float scl = 0.125f/ssum;
        #pragma unroll
        for(int i=0;i<16;i++) qlT[(seg+i)*68 + r] = vals[i]*scl;
    }
    __syncthreads();
    int e4 = (t & 15) * 4, r4 = (t >> 4) * 4;
    float acc[4][4] = {};
    for(int d=0; d<64; d++){
        float4 q4 = *(const float4*)&qlT[d*68 + r4];
        float4 c4 = *(const float4*)&cl[d][e4];
        acc[0][0] += q4.x*c4.x; acc[0][1] += q4.x*c4.y; acc[0][2] += q4.x*c4.z; acc[0][3] += q4.x*c4.w;
        acc[1][0] += q4.y*c4.x; acc[1][1] += q4.y*c4.y; acc[1][2] += q4.y*c4.z; acc[1][3] += q4.y*c4.w;
        acc[2][0] += q4.z*c4.x; acc[2][1] += q4.z*c4.y; acc[2][2] += q4.z*c4.z; acc[2][3] += q4.z*c4.w;
        acc[3][0] += q4.w*c4.x; acc[3][1] += q4.w*c4.y; acc[3][2] += q4.w*c4.z; acc[3][3] += q4.w*c4.w;
    }
    #pragma unroll
    for(int i=0;i<4;i++){
        ushort4 o;
        o.x = f2b(acc[i][0]); o.y = f2b(acc[i][1]); o.z = f2b(acc[i][2]); o.w = f2b(acc[i][3]);
        *(ushort4*)(abuf + (size_t)(rg*64 + r4 + i)*DD + h*64 + e4) = o;
    }
}

// ---------------------------------------------------------------- launch
extern "C" void kernel_launch(void* const* d_in, const int* in_sizes, int n_in,
                              void* d_out, int out_size, void* d_ws, size_t ws_size,
                              hipStream_t stream)
{
    const float* x     = (const float*)d_in[0];
    const float* ln1_g = (const float*)d_in[1];
    const float* ln1_b = (const float*)d_in[2];
    const float* w_qkv = (const float*)d_in[3];
    const float* w_out = (const float*)d_in[4];
    const float* b_out = (const float*)d_in[5];
    const float* ln2_g = (const float*)d_in[6];
    const float* ln2_b = (const float*)d_in[7];
    const float* w1    = (const float*)d_in[8];
    const float* b1    = (const float*)d_in[9];
    const float* w2    = (const float*)d_in[10];
    const float* b2    = (const float*)d_in[11];
    const float* w3    = (const float*)d_in[12];
    const float* b3    = (const float*)d_in[13];

    // ---- workspace layout (aliases temporally disjoint) ----
    char* ws = (char*)d_ws;
    unsigned short* wqkvT = (unsigned short*)(ws + 0);            // 6291456 B
    unsigned short* woutT = (unsigned short*)(ws + 6291456);      // 2097152 B
    unsigned short* w1T   = (unsigned short*)(ws + 8388608);      // 4194304 B
    unsigned short* w2T   = (unsigned short*)(ws + 12582912);     // 8388608 B
    unsigned short* w3T   = (unsigned short*)(ws + 20971520);     // 4194304 B
    unsigned short* Hbuf  = (unsigned short*)(ws + 25165824);     // 32 MB (ln1 out; later Abuf/H2)
    unsigned short* QKV   = (unsigned short*)(ws + 58720256);     // 96 MB (dead after attn_heads)
    float*          EP    = (float*)(ws + 159383552);             // 16 MB (attn phase)
    float*          CS    = (float*)(ws + 176160768);             // 256 KB
    float*          CTXF  = (float*)(ws + 176422912);             // 1 MB
    // phase 2 aliases:
    unsigned short* Abuf  = Hbuf;
    unsigned short* X2    = (unsigned short*)(ws + 58720256);     // x+attn bf16 [M,1024]
    unsigned short* H2    = Hbuf;
    unsigned short* Y1    = (unsigned short*)d_out;               // [M,2048] bf16 = out buffer
    unsigned short* Y2    = (unsigned short*)(ws + 125829120);    // 64 MB

    dim3 tb(32, 8);
    transpose_cvt<<<dim3(3072/32, 1024/32), tb, 0, stream>>>(w_qkv, wqkvT, 1024, 3072);
    transpose_cvt<<<dim3(1024/32, 1024/32), tb, 0, stream>>>(w_out, woutT, 1024, 1024);
    transpose_cvt<<<dim3(2048/32, 1024/32), tb, 0, stream>>>(w1,    w1T,   1024, 2048);
    transpose_cvt<<<dim3(2048/32, 2048/32), tb, 0, stream>>>(w2,    w2T,   2048, 2048);
    transpose_cvt<<<dim3(1024/32, 2048/32), tb, 0, stream>>>(w3,    w3T,   2048, 1024);

    ln_kernel<0><<<MM, 256, 0, stream>>>(x, ln1_g, ln1_b, Hbuf, 1);

    gemm256<0><<<dim3(3072/256, MM/256), 512, 0, stream>>>(Hbuf, wqkvT, QKV, nullptr, nullptr, MM, 3072, 1024);

    ctx_partial<<<dim3(16, HH, BB), 256, 0, stream>>>(QKV, EP, CS);
    ctx_reduce<<<BB*HH, 256, 0, stream>>>(EP, CS, CTXF);
    attn_heads<<<dim3(256, HH), 256, 0, stream>>>(QKV, CTXF, Abuf);

    gemm256<2><<<dim3(1024/256, MM/256), 512, 0, stream>>>(Abuf, woutT, X2, b_out, x, MM, 1024, 1024);

    ln_kernel<1><<<MM, 256, 0, stream>>>(X2, ln2_g, ln2_b, H2, 0);

    gemm256<1><<<dim3(2048/256, MM/256), 512, 0, stream>>>(H2, w1T, Y1, b1, nullptr, MM, 2048, 1024);
    gemm256<1><<<dim3(2048/256, MM/256), 512, 0, stream>>>(Y1, w2T, Y2, b2, nullptr, MM, 2048, 2048);
    gemm256<3><<<dim3(1024/256, MM/256), 512, 0, stream>>>(Y2, w3T, d_out, b3, X2, MM, 1024, 2048);
}

// Round 3
// 739.868 us; speedup vs baseline: 1.0081x; 1.0081x over previous
//
#include <hip/hip_runtime.h>
#include <cstdint>
#include <cstddef>

// Problem constants
#define BB 4
#define SS 4096
#define DD 1024
#define HH 16
#define MM (BB*SS)          // 16384 rows

typedef __bf16 bf16x8 __attribute__((ext_vector_type(8)));
typedef float  f32x4  __attribute__((ext_vector_type(4)));

__device__ __forceinline__ float b2f(unsigned short h){
    union { unsigned int u; float f; } c; c.u = ((unsigned int)h) << 16; return c.f;
}
__device__ __forceinline__ float b2f_u(unsigned int u16){
    union { unsigned int u; float f; } c; c.u = u16 << 16; return c.f;
}
__device__ __forceinline__ unsigned short f2b(float f){
    union { float f; unsigned int u; } c; c.f = f;
    unsigned int u = c.u + 0x7FFFu + ((c.u >> 16) & 1u);   // RNE
    return (unsigned short)(u >> 16);
}

// ---------------------------------------------------------------- transpose+cvt
__global__ void transpose_cvt(const float* __restrict__ src, unsigned short* __restrict__ dst,
                              int K, int N){
    __shared__ float tile[32][33];
    int kb = blockIdx.y*32, nb = blockIdx.x*32;
    int tx = threadIdx.x, ty = threadIdx.y;
    for(int i=0;i<32;i+=8) tile[ty+i][tx] = src[(size_t)(kb+ty+i)*N + nb+tx];
    __syncthreads();
    for(int i=0;i<32;i+=8) dst[(size_t)(nb+ty+i)*K + kb+tx] = f2b(tile[tx][ty+i]);
}

// ---------------------------------------------------------------- layernorm (+ optional sinusoidal PE)
template<int INBF>
__global__ __launch_bounds__(256) void ln_kernel(const void* __restrict__ xin,
                                                 const float* __restrict__ g,
                                                 const float* __restrict__ bta,
                                                 unsigned short* __restrict__ out,
                                                 int add_pe){
    int row = blockIdx.x;
    int t = threadIdx.x;
    float4 v;
    if (INBF == 0) {
        v = ((const float4*)((const float*)xin + (size_t)row*DD))[t];
    } else {
        ushort4 u = ((const ushort4*)((const unsigned short*)xin + (size_t)row*DD))[t];
        v.x = b2f(u.x); v.y = b2f(u.y); v.z = b2f(u.z); v.w = b2f(u.w);
    }
    float s = v.x+v.y+v.z+v.w;
    float q = v.x*v.x+v.y*v.y+v.z*v.z+v.w*v.w;
    for(int off=32; off>0; off>>=1){ s += __shfl_xor(s, off); q += __shfl_xor(q, off); }
    __shared__ float red[8];
    int wv = t>>6, ln = t&63;
    if(ln==0){ red[wv] = s; red[4+wv] = q; }
    __syncthreads();
    s = red[0]+red[1]+red[2]+red[3];
    q = red[4]+red[5]+red[6]+red[7];
    float mu = s * (1.0f/1024.0f);
    float var = q * (1.0f/1024.0f) - mu*mu;
    float rs = rsqrtf(var + 1e-6f);
    int d0 = t*4;
    float4 gg = ((const float4*)g)[t];
    float4 bb = ((const float4*)bta)[t];
    float o0 = (v.x-mu)*rs*gg.x + bb.x;
    float o1 = (v.y-mu)*rs*gg.y + bb.y;
    float o2 = (v.z-mu)*rs*gg.z + bb.z;
    float o3 = (v.w-mu)*rs*gg.w + bb.w;
    if(add_pe){
        int sidx = row & (SS-1);
        const float cfac = -0.008994473019508968f;   // -ln(10000)/1024
        float a0 = (float)sidx * expf(cfac * (float)(d0));
        float a1 = (float)sidx * expf(cfac * (float)(d0 + 2));
        o0 += sinf(a0); o1 += cosf(a0);
        o2 += sinf(a1); o3 += cosf(a1);
    }
    ushort4 o;
    o.x = f2b(o0); o.y = f2b(o1); o.z = f2b(o2); o.w = f2b(o3);
    *(ushort4*)(out + (size_t)row*DD + d0) = o;
}

// ---------------------------------------------------------------- 256x256 8-phase bf16 MFMA GEMM (v3: read-ahead)
// C = A[M,K] * Bt[N,K]^T.  8 waves (2M x 4N), per-wave C = 128x64, BK=64, 2 K-tiles/iter.
// LDS regions (16 KiB each): A[d*2+h] holds rows {wr*128+h*64+[0,64)}, B[d*2+q] holds {wc*64+q*32+[0,32)}.
// Register pipeline: B (U/V ping-pong) and A-lead (L0/L1, mi 0..1) read ONE PHASE AHEAD of their MFMA;
// A-tail (T, mi 2..3) read same-phase, consumed by the LAST 8 MFMAs of the cluster (latency hidden
// behind the first 8). One s_barrier per phase; counted vmcnt(4/6) 4x/iter (never 0 in loop).
// Stage schedule keeps >=2-phase gap between a region's last read and its re-stage (WAR), and every
// new-data read is covered by a prior counted-vmcnt+barrier (RAW).  No asm lgkmcnt: compiler inserts
// exact per-register waits for ds_read->MFMA deps.

#define BARX __builtin_amdgcn_s_barrier()
#define SCB  __builtin_amdgcn_sched_barrier(0)
#define VM6  asm volatile("s_waitcnt vmcnt(6)" ::: "memory")
#define VM4  asm volatile("s_waitcnt vmcnt(4)" ::: "memory")
#define PRIO1 __builtin_amdgcn_s_setprio(1)
#define PRIO0 __builtin_amdgcn_s_setprio(0)

// stage one A half-tile (region D*2+H) from k-offset KS: 2 x global_load_lds (16B/lane)
#define STGA(D, H, KS) { \
    const unsigned short* _s0 = baseA + (size_t)((H)*64)*K + (KS); \
    const unsigned short* _s1 = baseA + (size_t)((H)*64+128)*K + (KS); \
    char* _d = ((char*)lA) + (((D)*2+(H))<<14) + wbase; \
    __builtin_amdgcn_global_load_lds((const __attribute__((address_space(1))) void*)_s0, \
        (__attribute__((address_space(3))) void*)_d, 16, 0, 0); \
    __builtin_amdgcn_global_load_lds((const __attribute__((address_space(1))) void*)_s1, \
        (__attribute__((address_space(3))) void*)(_d + 8192), 16, 0, 0); }

#define STGB(D, Q, KS) { \
    const unsigned short* _s0 = baseB + (size_t)((Q)*32)*K + (KS); \
    const unsigned short* _s1 = baseB + (size_t)((Q)*32+128)*K + (KS); \
    char* _d = ((char*)lB) + (((D)*2+(Q))<<14) + wbase; \
    __builtin_amdgcn_global_load_lds((const __attribute__((address_space(1))) void*)_s0, \
        (__attribute__((address_space(3))) void*)_d, 16, 0, 0); \
    __builtin_amdgcn_global_load_lds((const __attribute__((address_space(1))) void*)_s1, \
        (__attribute__((address_space(3))) void*)(_d + 8192), 16, 0, 0); }

// load 2 A-fragments (rows MI0,MI0+1; both kk) from region D*2+H
#define LDAm(DST, D, H, MI0) { \
    const char* _p = ((const char*)lA) + (((D)*2+(H))<<14) + rbaseA; \
    DST[0][0] = *(const bf16x8*)(_p + ((MI0)<<11) + kb0); \
    DST[0][1] = *(const bf16x8*)(_p + ((MI0)<<11) + kb1); \
    DST[1][0] = *(const bf16x8*)(_p + (((MI0)+1)<<11) + kb0); \
    DST[1][1] = *(const bf16x8*)(_p + (((MI0)+1)<<11) + kb1); }

// load 2 B-fragments (nj 0,1; both kk) from region D*2+Q
#define LDBm(DST, D, Q) { \
    const char* _p = ((const char*)lB) + (((D)*2+(Q))<<14) + rbaseB; \
    DST[0][0] = *(const bf16x8*)(_p + kb0); \
    DST[0][1] = *(const bf16x8*)(_p + kb1); \
    DST[1][0] = *(const bf16x8*)(_p + 2048 + kb0); \
    DST[1][1] = *(const bf16x8*)(_p + 2048 + kb1); }

// 16-MFMA quadrant: lead pair (LS, read last phase) first, tail pair (TS, read this phase) last
#define MMQ(LS, TS, BS, QH, QB) { \
    _Pragma("unroll") \
    for (int mi = 0; mi < 2; mi++) \
    _Pragma("unroll") \
    for (int nj = 0; nj < 2; nj++) \
    _Pragma("unroll") \
    for (int kk = 0; kk < 2; kk++) \
        acc[(QH)*4+mi][(QB)*2+nj] = __builtin_amdgcn_mfma_f32_16x16x32_bf16( \
            LS[mi][kk], BS[nj][kk], acc[(QH)*4+mi][(QB)*2+nj], 0, 0, 0); \
    _Pragma("unroll") \
    for (int mi = 0; mi < 2; mi++) \
    _Pragma("unroll") \
    for (int nj = 0; nj < 2; nj++) \
    _Pragma("unroll") \
    for (int kk = 0; kk < 2; kk++) \
        acc[(QH)*4+2+mi][(QB)*2+nj] = __builtin_amdgcn_mfma_f32_16x16x32_bf16( \
            TS[mi][kk], BS[nj][kk], acc[(QH)*4+2+mi][(QB)*2+nj], 0, 0, 0); }

template<int EPI>
__global__ __launch_bounds__(512, 2) void gemm256(
        const unsigned short* __restrict__ A,
        const unsigned short* __restrict__ Bt,
        void* __restrict__ Cout,
        const float* __restrict__ bias,
        const void* __restrict__ resid,
        int M, int N, int K)
{
    __shared__ __align__(16) unsigned short lA[4*128*64];   // 64 KiB (4 regions)
    __shared__ __align__(16) unsigned short lB[4*128*64];   // 64 KiB

    const int tid  = threadIdx.x;
    const int lane = tid & 63;
    const int wave = tid >> 6;        // 0..7
    const int quad = lane >> 4;
    const int l16  = lane & 15;
    const int wr = wave >> 2;         // 0..1 (M)
    const int wc = wave & 3;          // 0..3 (N)

    // XCD-aware bijective tile swizzle (all grids here have nwg % 8 == 0)
    int gn  = gridDim.x;
    int lin = blockIdx.y * gn + blockIdx.x;
    int xcd = lin & 7;
    int j   = lin >> 3;
    int mt  = xcd + 8*(j/gn);
    int nt  = j - (j/gn)*gn;
    const int m0 = mt * 256;
    const int n0 = nt * 256;

    // stage source bases (per-lane); uniform (h,jj,ks) deltas added per call
    const int r8  = tid >> 3;                               // 0..63
    const int kcE = ((tid & 7) ^ (r8 & 7)) << 3;            // inverse-swizzle elem offset
    const unsigned short* baseA = A  + ((size_t)(m0 + r8) * K + kcE);
    const int gb0 = ((r8 >> 5) << 6) + (r8 & 31);
    const unsigned short* baseB = Bt + ((size_t)(n0 + gb0) * K + kcE);
    const int wbase = wave << 10;                           // lanes add lane*16

    // ds-read addressing
    const int rbaseA = (wr*64 + l16) * 128;
    const int rbaseB = (wc*32 + l16) * 128;
    const int kb0 = (quad*16)      ^ ((l16 & 7) << 4);
    const int kb1 = (64 + quad*16) ^ ((l16 & 7) << 4);

    f32x4 acc[8][4] = {};             // [h*4+mi][q*2+nj]
    bf16x8 L0[2][2], L1[2][2], T[2][2], U[2][2], V[2][2];

    // ---- prologue: stage d0 (all 4 halves) + d1.A0, d1.B1
    STGA(0,0, 0); STGB(0,1, 0); STGB(0,0, 0); STGA(0,1, 0);
    STGA(1,0, 64); STGB(1,1, 64);
    VM6;                               // first 6 loads (d0.A0, d0.B1, d0.B0) landed
    BARX; SCB;
    LDAm(L0, 0,0, 0);                  // A0 lead (for p1)
    LDBm(U,  0,0);                     // B0      (for p1)

    const int NIT = K >> 7;            // 2 K-tiles per iteration
    for (int it = 0; it < NIT; it++) {
        int ka  = it << 7;
        int kd1 = ka + 64;
        int kc2 = ka + 128; if (kc2 >= K) kc2 = 0;
        int kc3 = ka + 192; if (kc3 >= K) kc3 = 0;

        // p1: Q1(d0)=(A0,B0)
        STGB(1,0, kd1);                         // d1.B0
        LDAm(T, 0,0, 2); LDBm(V, 0,1);          // A0 tail (now), B1 (ahead)
        PRIO1; MMQ(L0, T, U, 0,0); PRIO0;
        VM6; BARX; SCB;
        // p2: Q2(d0)=(A0,B1)
        STGA(1,1, kd1);                         // d1.A1
        LDAm(L1, 0,1, 0);                       // A1 lead (ahead)
        PRIO1; MMQ(L0, T, V, 0,1); PRIO0;
        BARX; SCB;
        // p3: Q3(d0)=(A1,B1)
        STGA(0,0, kc2);                         // d0'.A0
        LDAm(T, 0,1, 2); LDBm(U, 0,0);          // A1 tail (now), B0 re-read (ahead)
        PRIO1; MMQ(L1, T, V, 1,1); PRIO0;
        VM4; BARX; SCB;
        // p4: Q4(d0)=(A1,B0)
        STGB(0,1, kc2);                         // d0'.B1
        LDAm(L0, 1,0, 0); LDBm(V, 1,0);         // d1.A0 lead, d1.B0 (ahead)
        PRIO1; MMQ(L1, T, U, 1,0); PRIO0;
        BARX; SCB;
        // p5: Q1(d1)=(A0,B0)
        STGB(0,0, kc2);                         // d0'.B0
        LDAm(T, 1,0, 2); LDBm(U, 1,1);          // d1.A0 tail (now), d1.B1 (ahead)
        PRIO1; MMQ(L0, T, V, 0,0); PRIO0;
        VM6; BARX; SCB;
        // p6: Q2(d1)=(A0,B1)
        STGA(0,1, kc2);                         // d0'.A1
        LDAm(L1, 1,1, 0);                       // d1.A1 lead (ahead)
        PRIO1; MMQ(L0, T, U, 0,1); PRIO0;
        BARX; SCB;
        // p7: Q3(d1)=(A1,B1)
        STGA(1,0, kc3);                         // d1'.A0
        LDAm(T, 1,1, 2); LDBm(V, 1,0);          // d1.A1 tail (now), d1.B0 re-read (ahead)
        PRIO1; MMQ(L1, T, U, 1,1); PRIO0;
        VM4; BARX; SCB;
        // p8: Q4(d1)=(A1,B0)
        STGB(1,1, kc3);                         // d1'.B1
        LDAm(L0, 0,0, 0); LDBm(U, 0,0);         // d0'.A0 lead, d0'.B0 (ahead)
        PRIO1; MMQ(L1, T, V, 1,0); PRIO0;
        BARX; SCB;
    }
    asm volatile("s_waitcnt vmcnt(0)" ::: "memory");   // drain before exit

    // ---- epilogue
    #pragma unroll
    for (int qm = 0; qm < 8; qm++) {
        int grow0 = m0 + wr*128 + (qm>>2)*64 + (qm&3)*16 + quad*4;
        #pragma unroll
        for (int r = 0; r < 4; r++) {
            int grow = grow0 + r;
            #pragma unroll
            for (int ni = 0; ni < 4; ni++) {
                int gcol = n0 + wc*64 + ni*16 + l16;
                float v = acc[qm][ni][r];
                size_t idx = (size_t)grow * N + gcol;
                if (EPI == 0) {
                    ((unsigned short*)Cout)[idx] = f2b(v);
                } else if (EPI == 1) {
                    v += bias[gcol];
                    v = 0.5f * v * (1.0f + erff(v * 0.70710678118654752f));
                    ((unsigned short*)Cout)[idx] = f2b(v);
                } else if (EPI == 2) {
                    v += bias[gcol] + ((const float*)resid)[idx];
                    ((unsigned short*)Cout)[idx] = f2b(v);
                } else {
                    v += bias[gcol] + b2f(((const unsigned short*)resid)[idx]);
                    ((float*)Cout)[idx] = v;
                }
            }
        }
    }
}

// ---------------------------------------------------------------- context partials (k-softmax folded)
__global__ __launch_bounds__(256) void ctx_partial(const unsigned short* __restrict__ qkv,
                                                   float* __restrict__ EP,
                                                   float* __restrict__ CS){
    int sc = blockIdx.x, h = blockIdx.y, b = blockIdx.z;
    int t = threadIdx.x;
    __shared__ __align__(16) float kl[64][64];   // exp(k)
    __shared__ __align__(16) float vl[64][64];
    __shared__ float csred[4][64];
    float acc[4][4] = {};
    float cspart = 0.0f;
    int e4 = (t & 15) * 4, d4 = (t >> 4) * 4;
    int dcol = t & 63, schunk = t >> 6;
    for(int s0 = 0; s0 < 256; s0 += 64){
        __syncthreads();
        #pragma unroll
        for(int j=0;j<2;j++){
            int lin = t + 256*j;
            int row = lin >> 3;
            int c8  = (lin & 7) * 8;
            size_t gr = (size_t)(b*SS + sc*256 + s0 + row);
            uint4 kv = *(const uint4*)(qkv + gr*3072 + DD + h*64 + c8);
            float4 ka, kb2;
            ka.x = expf(b2f_u(kv.x & 0xFFFFu)); ka.y = expf(b2f_u(kv.x >> 16));
            ka.z = expf(b2f_u(kv.y & 0xFFFFu)); ka.w = expf(b2f_u(kv.y >> 16));
            kb2.x = expf(b2f_u(kv.z & 0xFFFFu)); kb2.y = expf(b2f_u(kv.z >> 16));
            kb2.z = expf(b2f_u(kv.w & 0xFFFFu)); kb2.w = expf(b2f_u(kv.w >> 16));
            *(float4*)&kl[row][c8]   = ka;
            *(float4*)&kl[row][c8+4] = kb2;
            uint4 vv = *(const uint4*)(qkv + gr*3072 + 2*DD + h*64 + c8);
            float4 va, vb;
            va.x = b2f_u(vv.x & 0xFFFFu); va.y = b2f_u(vv.x >> 16);
            va.z = b2f_u(vv.y & 0xFFFFu); va.w = b2f_u(vv.y >> 16);
            vb.x = b2f_u(vv.z & 0xFFFFu); vb.y = b2f_u(vv.z >> 16);
            vb.z = b2f_u(vv.w & 0xFFFFu); vb.w = b2f_u(vv.w >> 16);
            *(float4*)&vl[row][c8]   = va;
            *(float4*)&vl[row][c8+4] = vb;
        }
        __syncthreads();
        #pragma unroll
        for(int i=0;i<16;i++) cspart += kl[schunk*16+i][dcol];
        for(int s=0;s<64;s++){
            float4 k4 = *(const float4*)&kl[s][d4];
            float4 v4 = *(const float4*)&vl[s][e4];
            acc[0][0] += k4.x*v4.x; acc[0][1] += k4.x*v4.y; acc[0][2] += k4.x*v4.z; acc[0][3] += k4.x*v4.w;
            acc[1][0] += k4.y*v4.x; acc[1][1] += k4.y*v4.y; acc[1][2] += k4.y*v4.z; acc[1][3] += k4.y*v4.w;
            acc[2][0] += k4.z*v4.x; acc[2][1] += k4.z*v4.y; acc[2][2] += k4.z*v4.z; acc[2][3] += k4.z*v4.w;
            acc[3][0] += k4.w*v4.x; acc[3][1] += k4.w*v4.y; acc[3][2] += k4.w*v4.z; acc[3][3] += k4.w*v4.w;
        }
    }
    int slot = (b*HH + h)*16 + sc;
    float* ep = EP + (size_t)slot*4096;
    #pragma unroll
    for(int i=0;i<4;i++)
        *(float4*)&ep[(d4+i)*64 + e4] = *(float4*)&acc[i][0];
    csred[schunk][dcol] = cspart;
    __syncthreads();
    if(t < 64) CS[slot*64 + t] = csred[0][t]+csred[1][t]+csred[2][t]+csred[3][t];
}

// ---------------------------------------------------------------- reduce 16 slots, divide by colsum
__global__ __launch_bounds__(256) void ctx_reduce(const float* __restrict__ EP,
                                                  const float* __restrict__ CS,
                                                  float* __restrict__ CTXF){
    int bh = blockIdx.x;
    int t = threadIdx.x;
    int d = t >> 2, e0 = (t & 3) * 16;
    float cs = 0.0f;
    #pragma unroll
    for(int sl=0; sl<16; sl++) cs += CS[(bh*16+sl)*64 + d];
    float inv = 1.0f/cs;
    #pragma unroll
    for(int i=0;i<16;i++){
        float s = 0.0f;
        #pragma unroll
        for(int sl=0; sl<16; sl++) s += EP[(size_t)(bh*16+sl)*4096 + d*64 + e0 + i];
        CTXF[(size_t)bh*4096 + d*64 + e0 + i] = s * inv;
    }
}

// ---------------------------------------------------------------- attn = softmax(q)/8 @ ctx  (q-softmax fused)
__global__ __launch_bounds__(256) void attn_heads(const unsigned short* __restrict__ qkv,
                                                  const float* __restrict__ CTXF,
                                                  unsigned short* __restrict__ abuf){
    int rg = blockIdx.x, h = blockIdx.y;
    int b = rg >> 6;
    int t = threadIdx.x;
    __shared__ __align__(16) float cl[64][64];
    __shared__ __align__(16) float qlT[64*68];    // [d][r], row stride 68 floats
    const float* cb = CTXF + (size_t)(b*HH + h)*4096;
    for(int j=0;j<4;j++){
        int lin = t + 256*j;
        ((float4*)cl)[lin] = ((const float4*)cb)[lin];
    }
    {
        int r = t >> 2, seg = (t & 3) * 16;
        const unsigned short* qp = qkv + (size_t)(rg*64 + r)*3072 + h*64 + seg;
        float vals[16];
        float m = -1e30f;
        #pragma unroll
        for(int u=0; u<4; u++){
            ushort4 qv = *(const ushort4*)(qp + u*4);
            vals[u*4+0]=b2f(qv.x); vals[u*4+1]=b2f(qv.y); vals[u*4+2]=b2f(qv.z); vals[u*4+3]=b2f(qv.w);
        }
        #pragma unroll
        for(int i=0;i<16;i++) m = fmaxf(m, vals[i]);
        m = fmaxf(m, __shfl_xor(m, 1));
        m = fmaxf(m, __shfl_xor(m, 2));
        float ssum = 0.0f;
        #pragma unroll
        for(int i=0;i<16;i++){ vals[i] = expf(vals[i]-m); ssum += vals[i]; }
        ssum += __shfl_xor(ssum, 1);
        ssum += __shfl_xor(ssum, 2);
        float scl = 0.125f/ssum;
        #pragma unroll
        for(int i=0;i<16;i++) qlT[(seg+i)*68 + r] = vals[i]*scl;
    }
    __syncthreads();
    int e4 = (t & 15) * 4, r4 = (t >> 4) * 4;
    float acc[4][4] = {};
    for(int d=0; d<64; d++){
        float4 q4 = *(const float4*)&qlT[d*68 + r4];
        float4 c4 = *(const float4*)&cl[d][e4];
        acc[0][0] += q4.x*c4.x; acc[0][1] += q4.x*c4.y; acc[0][2] += q4.x*c4.z; acc[0][3] += q4.x*c4.w;
        acc[1][0] += q4.y*c4.x; acc[1][1] += q4.y*c4.y; acc[1][2] += q4.y*c4.z; acc[1][3] += q4.y*c4.w;
        acc[2][0] += q4.z*c4.x; acc[2][1] += q4.z*c4.y; acc[2][2] += q4.z*c4.z; acc[2][3] += q4.z*c4.w;
        acc[3][0] += q4.w*c4.x; acc[3][1] += q4.w*c4.y; acc[3][2] += q4.w*c4.z; acc[3][3] += q4.w*c4.w;
    }
    #pragma unroll
    for(int i=0;i<4;i++){
        ushort4 o;
        o.x = f2b(acc[i][0]); o.y = f2b(acc[i][1]); o.z = f2b(acc[i][2]); o.w = f2b(acc[i][3]);
        *(ushort4*)(abuf + (size_t)(rg*64 + r4 + i)*DD + h*64 + e4) = o;
    }
}

// ---------------------------------------------------------------- launch
extern "C" void kernel_launch(void* const* d_in, const int* in_sizes, int n_in,
                              void* d_out, int out_size, void* d_ws, size_t ws_size,
                              hipStream_t stream)
{
    const float* x     = (const float*)d_in[0];
    const float* ln1_g = (const float*)d_in[1];
    const float* ln1_b = (const float*)d_in[2];
    const float* w_qkv = (const float*)d_in[3];
    const float* w_out = (const float*)d_in[4];
    const float* b_out = (const float*)d_in[5];
    const float* ln2_g = (const float*)d_in[6];
    const float* ln2_b = (const float*)d_in[7];
    const float* w1    = (const float*)d_in[8];
    const float* b1    = (const float*)d_in[9];
    const float* w2    = (const float*)d_in[10];
    const float* b2    = (const float*)d_in[11];
    const float* w3    = (const float*)d_in[12];
    const float* b3    = (const float*)d_in[13];

    // ---- workspace layout (aliases temporally disjoint) ----
    char* ws = (char*)d_ws;
    unsigned short* wqkvT = (unsigned short*)(ws + 0);            // 6291456 B
    unsigned short* woutT = (unsigned short*)(ws + 6291456);      // 2097152 B
    unsigned short* w1T   = (unsigned short*)(ws + 8388608);      // 4194304 B
    unsigned short* w2T   = (unsigned short*)(ws + 12582912);     // 8388608 B
    unsigned short* w3T   = (unsigned short*)(ws + 20971520);     // 4194304 B
    unsigned short* Hbuf  = (unsigned short*)(ws + 25165824);     // 32 MB (ln1 out; later Abuf/H2)
    unsigned short* QKV   = (unsigned short*)(ws + 58720256);     // 96 MB (dead after attn_heads)
    float*          EP    = (float*)(ws + 159383552);             // 16 MB (attn phase)
    float*          CS    = (float*)(ws + 176160768);             // 256 KB
    float*          CTXF  = (float*)(ws + 176422912);             // 1 MB
    // phase 2 aliases:
    unsigned short* Abuf  = Hbuf;
    unsigned short* X2    = (unsigned short*)(ws + 58720256);     // x+attn bf16 [M,1024]
    unsigned short* H2    = Hbuf;
    unsigned short* Y1    = (unsigned short*)d_out;               // [M,2048] bf16 = out buffer
    unsigned short* Y2    = (unsigned short*)(ws + 125829120);    // 64 MB

    dim3 tb(32, 8);
    transpose_cvt<<<dim3(3072/32, 1024/32), tb, 0, stream>>>(w_qkv, wqkvT, 1024, 3072);
    transpose_cvt<<<dim3(1024/32, 1024/32), tb, 0, stream>>>(w_out, woutT, 1024, 1024);
    transpose_cvt<<<dim3(2048/32, 1024/32), tb, 0, stream>>>(w1,    w1T,   1024, 2048);
    transpose_cvt<<<dim3(2048/32, 2048/32), tb, 0, stream>>>(w2,    w2T,   2048, 2048);
    transpose_cvt<<<dim3(1024/32, 2048/32), tb, 0, stream>>>(w3,    w3T,   2048, 1024);

    ln_kernel<0><<<MM, 256, 0, stream>>>(x, ln1_g, ln1_b, Hbuf, 1);

    gemm256<0><<<dim3(3072/256, MM/256), 512, 0, stream>>>(Hbuf, wqkvT, QKV, nullptr, nullptr, MM, 3072, 1024);

    ctx_partial<<<dim3(16, HH, BB), 256, 0, stream>>>(QKV, EP, CS);
    ctx_reduce<<<BB*HH, 256, 0, stream>>>(EP, CS, CTXF);
    attn_heads<<<dim3(256, HH), 256, 0, stream>>>(QKV, CTXF, Abuf);

    gemm256<2><<<dim3(1024/256, MM/256), 512, 0, stream>>>(Abuf, woutT, X2, b_out, x, MM, 1024, 1024);

    ln_kernel<1><<<MM, 256, 0, stream>>>(X2, ln2_g, ln2_b, H2, 0);

    gemm256<1><<<dim3(2048/256, MM/256), 512, 0, stream>>>(H2, w1T, Y1, b1, nullptr, MM, 2048, 1024);
    gemm256<1><<<dim3(2048/256, MM/256), 512, 0, stream>>>(Y1, w2T, Y2, b2, nullptr, MM, 2048, 2048);
    gemm256<3><<<dim3(1024/256, MM/256), 512, 0, stream>>>(Y2, w3T, d_out, b3, X2, MM, 1024, 2048);
}